// Round 1
// baseline (102.105 us; speedup 1.0000x reference)
//
#include <hip/hip_runtime.h>
#include <math.h>

// Problem constants (from reference setup_inputs):
// B=256 graphs, A=64 atoms, E=128 edges, K=6 neighbors, H=256 channels.
#define NB 256
#define NA 64
#define NE 128
#define NK 6
#define NH 256

// Block = 256 threads = one b, 4 consecutive edges (64 lanes per edge, float4/lane).
// Threads 0..23 compute the 24 neighbor weights into LDS, then each 64-lane
// group gathers+sums 6 weighted rows of rep.
__global__ __launch_bounds__(256) void edge_msg_kernel(
    const float* __restrict__ rep,   // [B,E,H]
    const int*   __restrict__ pairs, // [B,E,2]
    const int*   __restrict__ nbrs,  // [B,E,K]
    const float* __restrict__ xyz,   // [B,A,3]
    float*       __restrict__ out)   // [B,E,H]
{
    const int b   = blockIdx.y;
    const int e0  = blockIdx.x * 4;
    const int tid = threadIdx.x;

    __shared__ float sw[4][NK];
    __shared__ int   snb[4][NK];

    if (tid < 4 * NK) {
        const int se = tid / NK;
        const int k  = tid % NK;
        const int e  = e0 + se;
        const int nb = nbrs[(b * NE + e) * NK + k];
        const int p0 = pairs[(b * NE + nb) * 2 + 0];
        const int p1 = pairs[(b * NE + nb) * 2 + 1];
        const float* x0 = xyz + ((size_t)b * NA + p0) * 3;
        const float* x1 = xyz + ((size_t)b * NA + p1) * 3;
        const float dx = x0[0] - x1[0];
        const float dy = x0[1] - x1[1];
        const float dz = x0[2] - x1[2];
        const float d2 = dx * dx + dy * dy + dz * dz;
        float inv = 1.0f / d2;          // IEEE divide (no fast-math): matches XLA
        if (isinf(inv)) inv = 0.0f;     // jnp.where(isinf(inv), 0, inv)
        sw[se][k]  = inv;
        snb[se][k] = nb;
    }
    __syncthreads();

    const int se   = tid >> 6;   // which of the 4 edges
    const int lane = tid & 63;   // float4 index within H=256 (64 * 4 floats)

    const float4* rep4 = (const float4*)(rep + (size_t)b * NE * NH);
    float4 acc = make_float4(0.f, 0.f, 0.f, 0.f);
#pragma unroll
    for (int k = 0; k < NK; ++k) {
        const float  w = sw[se][k];
        const float4 v = rep4[snb[se][k] * (NH / 4) + lane];
        acc.x += w * v.x;
        acc.y += w * v.y;
        acc.z += w * v.z;
        acc.w += w * v.w;
    }
    float4* out4 = (float4*)(out + ((size_t)b * NE + (e0 + se)) * NH);
    out4[lane] = acc;
}

extern "C" void kernel_launch(void* const* d_in, const int* in_sizes, int n_in,
                              void* d_out, int out_size, void* d_ws, size_t ws_size,
                              hipStream_t stream) {
    const float* rep   = (const float*)d_in[0]; // [1,B,E,H] fp32
    const int*   pairs = (const int*)  d_in[1]; // [B,E,2]
    const int*   nbrs  = (const int*)  d_in[2]; // [B,E,K]
    const float* xyz   = (const float*)d_in[3]; // [B,A,3]
    float*       out   = (float*)d_out;         // [1,B,E,H]

    dim3 grid(NE / 4, NB);   // 32 x 256 = 8192 blocks
    dim3 block(256);
    edge_msg_kernel<<<grid, block, 0, stream>>>(rep, pairs, nbrs, xyz, out);
}

// Round 2
// 95.067 us; speedup vs baseline: 1.0740x; 1.0740x over previous
//
#include <hip/hip_runtime.h>
#include <math.h>

// Problem constants (from reference setup_inputs):
// B=256 graphs, A=64 atoms, E=128 edges, K=6 neighbors, H=256 channels.
#define NB 256
#define NA 64
#define NE 128
#define NK 6
#define NH 256

// One block per b. Stage the whole rep[b] slice (E*H = 32768 floats = 128 KiB)
// in dynamic LDS (>64 KiB static limit, so extern __shared__), precompute all
// E edge weights, then each of the 4 waves produces 32 edges: 64 lanes x
// float4 over H, summing 6 LDS-gathered rows. Global reads become exactly
// compulsory (33.5 MB, fully coalesced); the 6x gather amplification is
// absorbed by LDS instead of L2.
__global__ __launch_bounds__(256, 1) void edge_msg_kernel(
    const float* __restrict__ rep,   // [B,E,H]
    const int*   __restrict__ pairs, // [B,E,2]
    const int*   __restrict__ nbrs,  // [B,E,K]
    const float* __restrict__ xyz,   // [B,A,3]
    float*       __restrict__ out)   // [B,E,H]
{
    extern __shared__ float smem[];
    float* s_rep = smem;                  // NE*NH floats (128 KiB)
    float* s_w   = smem + NE * NH;        // NE floats
    int*   s_nb  = (int*)(s_w + NE);      // NE*NK ints

    const int b   = blockIdx.x;
    const int tid = threadIdx.x;

    // --- stage neighbor indices (768 ints; 3 per thread) ---
    const int* nbr_b = nbrs + b * NE * NK;
#pragma unroll
    for (int i = tid; i < NE * NK; i += 256) s_nb[i] = nbr_b[i];

    // --- per-edge distance weights (threads 0..127) ---
    if (tid < NE) {
        const int p0 = pairs[(b * NE + tid) * 2 + 0];
        const int p1 = pairs[(b * NE + tid) * 2 + 1];
        const float* x0 = xyz + ((size_t)b * NA + p0) * 3;
        const float* x1 = xyz + ((size_t)b * NA + p1) * 3;
        const float dx = x0[0] - x1[0];
        const float dy = x0[1] - x1[1];
        const float dz = x0[2] - x1[2];
        const float d2 = dx * dx + dy * dy + dz * dz;
        float inv = 1.0f / d2;          // IEEE divide: matches XLA
        if (isinf(inv)) inv = 0.0f;     // jnp.where(isinf(inv), 0, inv)
        s_w[tid] = inv;
    }

    // --- copy rep[b] slice to LDS: 8192 float4, 32 per thread, 8-deep ILP ---
    const float4* g4 = (const float4*)(rep + (size_t)b * NE * NH);
    float4*       l4 = (float4*)s_rep;
#pragma unroll
    for (int i = 0; i < 32; i += 8) {
        float4 r[8];
#pragma unroll
        for (int j = 0; j < 8; ++j) r[j] = g4[tid + (i + j) * 256];
#pragma unroll
        for (int j = 0; j < 8; ++j) l4[tid + (i + j) * 256] = r[j];
    }
    __syncthreads();

    // --- compute: wave w handles edges [w*32, w*32+32) ---
    const int wid  = tid >> 6;
    const int lane = tid & 63;   // float4 index within H
    const float4* lrep4 = (const float4*)s_rep;
    float4* outb = (float4*)(out + (size_t)b * NE * NH);

#pragma unroll 4
    for (int ei = 0; ei < 32; ++ei) {
        const int e = wid * 32 + ei;
        float4 acc = make_float4(0.f, 0.f, 0.f, 0.f);
#pragma unroll
        for (int k = 0; k < NK; ++k) {
            const int   nb = s_nb[e * NK + k];   // wave-uniform -> LDS broadcast
            const float w  = s_w[nb];            // broadcast
            const float4 v = lrep4[nb * (NH / 4) + lane];  // contiguous 1 KiB/wave
            acc.x += w * v.x;
            acc.y += w * v.y;
            acc.z += w * v.z;
            acc.w += w * v.w;
        }
        outb[e * (NH / 4) + lane] = acc;
    }
}

extern "C" void kernel_launch(void* const* d_in, const int* in_sizes, int n_in,
                              void* d_out, int out_size, void* d_ws, size_t ws_size,
                              hipStream_t stream) {
    const float* rep   = (const float*)d_in[0]; // [1,B,E,H] fp32
    const int*   pairs = (const int*)  d_in[1]; // [B,E,2]
    const int*   nbrs  = (const int*)  d_in[2]; // [B,E,K]
    const float* xyz   = (const float*)d_in[3]; // [B,A,3]
    float*       out   = (float*)d_out;         // [1,B,E,H]

    const size_t lds_bytes = (size_t)(NE * NH + NE) * sizeof(float)
                           + (size_t)(NE * NK) * sizeof(int);  // 134656 B < 160 KiB
    edge_msg_kernel<<<dim3(NB), dim3(256), lds_bytes, stream>>>(rep, pairs, nbrs, xyz, out);
}